// Round 1
// baseline (9383.727 us; speedup 1.0000x reference)
//
#include <hip/hip_runtime.h>
#include <stdint.h>

#define V_ 16000
#define E_ 512
#define H_ 1024
#define B_ 32
#define T_ 64

__device__ __forceinline__ unsigned int fkey(float f) {
    unsigned int u = __float_as_uint(f);
    return (u & 0x80000000u) ? ~u : (u | 0x80000000u);
}

__global__ void init_kernel(const float* __restrict__ hidden,
                            float* __restrict__ h0, float* __restrict__ h1,
                            unsigned long long* __restrict__ tokpk) {
    int idx = blockIdx.x * blockDim.x + threadIdx.x;
    if (idx < B_ * H_) {
        h0[idx] = hidden[idx];
        h1[idx] = hidden[B_ * H_ + idx];
    }
    if (idx < T_ * B_) tokpk[idx] = 0ull;
}

// GRU cell kernel. Each block owns 4 hidden columns i; computes gates r,z,n for
// those columns over all 32 batch rows, then the combine, writing h_new.
// mode==1: x rows come from embed via tok gather; mode==0: x = xsrc rows [B][KX].
// Thread org: 256 thr = ks(8 K-splits) x [iloc(4) x bg(8, 4 batch each)].
// Accumulators per thread: 4 batch x {s_r, s_z, a_n(ih part), h_n(hh part)}.
template<int KX>
__global__ __launch_bounds__(256) void gru_kernel(
    const float* __restrict__ xsrc, const unsigned long long* __restrict__ tokprev,
    int t, int mode,
    const float* __restrict__ hprev,
    const float* __restrict__ Wih, const float* __restrict__ Whh,
    const float* __restrict__ bih, const float* __restrict__ bhh,
    float* __restrict__ hnew)
{
    const int tid  = threadIdx.x;
    const int ks   = tid >> 5;        // 0..7
    const int slot = tid & 31;        // 0..31
    const int iloc = slot >> 3;       // 0..3
    const int bg   = slot & 7;        // 0..7
    const int b0   = bg * 4;
    const int i    = blockIdx.x * 4 + iloc;

    const float* xb[4];
    #pragma unroll
    for (int j = 0; j < 4; j++) {
        if (mode) {
            int tok = 0;
            if (t > 0) {
                unsigned long long p = tokprev[b0 + j];
                tok = (int)(0xFFFFFFFFu - (unsigned int)(p & 0xFFFFFFFFull));
            }
            xb[j] = xsrc + (size_t)tok * KX;
        } else {
            xb[j] = xsrc + (size_t)(b0 + j) * KX;
        }
    }

    float sr[4] = {0,0,0,0}, sz[4] = {0,0,0,0}, an[4] = {0,0,0,0}, hn[4] = {0,0,0,0};

    // ---- x (input) part: rows of W_ih, K = KX ----
    {
        const float* wr = Wih + (size_t)(i) * KX;
        const float* wz = Wih + (size_t)(H_ + i) * KX;
        const float* wn = Wih + (size_t)(2 * H_ + i) * KX;
        const int kc = KX / 8;
        const int kend = (ks + 1) * kc;
        for (int k = ks * kc; k < kend; k += 4) {
            float4 w_r = *(const float4*)(wr + k);
            float4 w_z = *(const float4*)(wz + k);
            float4 w_n = *(const float4*)(wn + k);
            #pragma unroll
            for (int j = 0; j < 4; j++) {
                float4 a = *(const float4*)(xb[j] + k);
                sr[j] += w_r.x*a.x + w_r.y*a.y + w_r.z*a.z + w_r.w*a.w;
                sz[j] += w_z.x*a.x + w_z.y*a.y + w_z.z*a.z + w_z.w*a.w;
                an[j] += w_n.x*a.x + w_n.y*a.y + w_n.z*a.z + w_n.w*a.w;
            }
        }
    }
    // ---- h (recurrent) part: rows of W_hh, K = H ----
    {
        const float* wr = Whh + (size_t)(i) * H_;
        const float* wz = Whh + (size_t)(H_ + i) * H_;
        const float* wn = Whh + (size_t)(2 * H_ + i) * H_;
        const int kc = H_ / 8;  // 128
        const int kend = (ks + 1) * kc;
        for (int k = ks * kc; k < kend; k += 4) {
            float4 w_r = *(const float4*)(wr + k);
            float4 w_z = *(const float4*)(wz + k);
            float4 w_n = *(const float4*)(wn + k);
            #pragma unroll
            for (int j = 0; j < 4; j++) {
                const float* hb = hprev + (size_t)(b0 + j) * H_;
                float4 a = *(const float4*)(hb + k);
                sr[j] += w_r.x*a.x + w_r.y*a.y + w_r.z*a.z + w_r.w*a.w;
                sz[j] += w_z.x*a.x + w_z.y*a.y + w_z.z*a.z + w_z.w*a.w;
                hn[j] += w_n.x*a.x + w_n.y*a.y + w_n.z*a.z + w_n.w*a.w;
            }
        }
    }

    __shared__ float red[8][32][16];
    {
        float* dst = &red[ks][slot][0];
        #pragma unroll
        for (int j = 0; j < 4; j++) {
            dst[j]      = sr[j];
            dst[4 + j]  = sz[j];
            dst[8 + j]  = an[j];
            dst[12 + j] = hn[j];
        }
    }
    __syncthreads();
    if (ks == 0) {
        float tot[16];
        #pragma unroll
        for (int c = 0; c < 16; c++) {
            float s = 0.f;
            #pragma unroll
            for (int kk = 0; kk < 8; kk++) s += red[kk][slot][c];
            tot[c] = s;
        }
        const float b_r  = bih[i] + bhh[i];
        const float b_z  = bih[H_ + i] + bhh[H_ + i];
        const float b_an = bih[2 * H_ + i];
        const float b_hn = bhh[2 * H_ + i];
        #pragma unroll
        for (int j = 0; j < 4; j++) {
            const int b = b0 + j;
            float Sr = tot[j]      + b_r;
            float Sz = tot[4 + j]  + b_z;
            float An = tot[8 + j]  + b_an;
            float Hn = tot[12 + j] + b_hn;
            float r = 1.f / (1.f + expf(-Sr));
            float z = 1.f / (1.f + expf(-Sz));
            float n = tanhf(An + r * Hn);
            float hp = hprev[(size_t)b * H_ + i];
            hnew[(size_t)b * H_ + i] = (1.f - z) * n + z * hp;
        }
    }
}

// Logits + fused argmax. Block tile: 64 vocab cols x 32 batch. 256 thr =
// ks(2 K-splits) x [v4(16, 4 vocab each) x bg(8, 4 batch each)]. 16 acc/thread.
__global__ __launch_bounds__(256) void logits_kernel(
    const float* __restrict__ h1, const float* __restrict__ Wout,
    const float* __restrict__ bout, float* __restrict__ out_t,
    unsigned long long* __restrict__ tokpk_t)
{
    const int tid  = threadIdx.x;
    const int ks   = tid >> 7;        // 0..1
    const int slot = tid & 127;       // 0..127
    const int v4   = slot >> 3;       // 0..15
    const int bg   = slot & 7;        // 0..7
    const int b0   = bg * 4;
    const int v    = blockIdx.x * 64 + v4 * 4;

    float acc[4][4];
    #pragma unroll
    for (int vi = 0; vi < 4; vi++)
        #pragma unroll
        for (int j = 0; j < 4; j++) acc[vi][j] = 0.f;

    const float* wp[4];
    const float* ap[4];
    #pragma unroll
    for (int vi = 0; vi < 4; vi++) wp[vi] = Wout + (size_t)(v + vi) * H_;
    #pragma unroll
    for (int j = 0; j < 4; j++) ap[j] = h1 + (size_t)(b0 + j) * H_;

    const int k0 = ks * (H_ / 2), k1 = k0 + (H_ / 2);
    for (int k = k0; k < k1; k += 4) {
        float4 aa[4], ww[4];
        #pragma unroll
        for (int j = 0; j < 4; j++) aa[j] = *(const float4*)(ap[j] + k);
        #pragma unroll
        for (int vi = 0; vi < 4; vi++) ww[vi] = *(const float4*)(wp[vi] + k);
        #pragma unroll
        for (int vi = 0; vi < 4; vi++)
            #pragma unroll
            for (int j = 0; j < 4; j++)
                acc[vi][j] += ww[vi].x*aa[j].x + ww[vi].y*aa[j].y
                            + ww[vi].z*aa[j].z + ww[vi].w*aa[j].w;
    }

    __shared__ float red[128][16];
    __shared__ unsigned long long am[32][16];
    if (ks == 1) {
        #pragma unroll
        for (int vi = 0; vi < 4; vi++)
            #pragma unroll
            for (int j = 0; j < 4; j++) red[slot][vi * 4 + j] = acc[vi][j];
    }
    __syncthreads();
    if (ks == 0) {
        #pragma unroll
        for (int vi = 0; vi < 4; vi++)
            #pragma unroll
            for (int j = 0; j < 4; j++) acc[vi][j] += red[slot][vi * 4 + j];
        float bo[4];
        #pragma unroll
        for (int vi = 0; vi < 4; vi++) bo[vi] = bout[v + vi];
        #pragma unroll
        for (int vi = 0; vi < 4; vi++)
            #pragma unroll
            for (int j = 0; j < 4; j++) acc[vi][j] += bo[vi];

        // store logits (float4 along vocab)
        #pragma unroll
        for (int j = 0; j < 4; j++) {
            float4 o = make_float4(acc[0][j], acc[1][j], acc[2][j], acc[3][j]);
            *(float4*)(out_t + (size_t)(b0 + j) * V_ + v) = o;
        }
        // local argmax per batch over this thread's 4 vocab cols
        #pragma unroll
        for (int j = 0; j < 4; j++) {
            unsigned long long best = 0ull;
            #pragma unroll
            for (int vi = 0; vi < 4; vi++) {
                unsigned long long p =
                    ((unsigned long long)fkey(acc[vi][j]) << 32)
                    | (unsigned long long)(0xFFFFFFFFu - (unsigned int)(v + vi));
                best = (p > best) ? p : best;
            }
            am[b0 + j][v4] = best;
        }
    }
    __syncthreads();
    if (tid < 32) {
        unsigned long long best = 0ull;
        #pragma unroll
        for (int q = 0; q < 16; q++) {
            unsigned long long p = am[tid][q];
            best = (p > best) ? p : best;
        }
        atomicMax(&tokpk_t[tid], best);
    }
}

extern "C" void kernel_launch(void* const* d_in, const int* in_sizes, int n_in,
                              void* d_out, int out_size, void* d_ws, size_t ws_size,
                              hipStream_t stream) {
    const float* hidden = (const float*)d_in[0];
    const float* embed  = (const float*)d_in[1];
    const float* Wih0   = (const float*)d_in[2];
    const float* Whh0   = (const float*)d_in[3];
    const float* bih0   = (const float*)d_in[4];
    const float* bhh0   = (const float*)d_in[5];
    const float* Wih1   = (const float*)d_in[6];
    const float* Whh1   = (const float*)d_in[7];
    const float* bih1   = (const float*)d_in[8];
    const float* bhh1   = (const float*)d_in[9];
    const float* Wout   = (const float*)d_in[10];
    const float* bout   = (const float*)d_in[11];
    float* out = (float*)d_out;

    float* ws = (float*)d_ws;
    float* h0buf = ws;                       // [2][B][H]
    float* h1buf = ws + 2 * B_ * H_;         // [2][B][H]
    unsigned long long* tokpk =
        (unsigned long long*)(ws + 4 * B_ * H_);  // [T][B]

    init_kernel<<<128, 256, 0, stream>>>(hidden, h0buf, h1buf, tokpk);

    for (int t = 0; t < T_; t++) {
        const int rp = t & 1, wpar = (t + 1) & 1;
        const unsigned long long* tokprev = tokpk + (size_t)(t > 0 ? t - 1 : 0) * B_;

        gru_kernel<E_><<<H_ / 4, 256, 0, stream>>>(
            embed, tokprev, t, /*mode=*/1,
            h0buf + (size_t)rp * B_ * H_,
            Wih0, Whh0, bih0, bhh0,
            h0buf + (size_t)wpar * B_ * H_);

        gru_kernel<H_><<<H_ / 4, 256, 0, stream>>>(
            h0buf + (size_t)wpar * B_ * H_, nullptr, 0, /*mode=*/0,
            h1buf + (size_t)rp * B_ * H_,
            Wih1, Whh1, bih1, bhh1,
            h1buf + (size_t)wpar * B_ * H_);

        logits_kernel<<<V_ / 64, 256, 0, stream>>>(
            h1buf + (size_t)wpar * B_ * H_, Wout, bout,
            out + (size_t)t * B_ * V_,
            tokpk + (size_t)t * B_);
    }
}

// Round 3
// 9124.899 us; speedup vs baseline: 1.0284x; 1.0284x over previous
//
#include <hip/hip_runtime.h>
#include <stdint.h>

#define V_ 16000
#define E_ 512
#define H_ 1024
#define B_ 32
#define T_ 64

typedef float f32x4 __attribute__((ext_vector_type(4)));

__device__ __forceinline__ unsigned int fkey(float f) {
    unsigned int u = __float_as_uint(f);
    return (u & 0x80000000u) ? ~u : (u | 0x80000000u);
}

__global__ void init_kernel(const float* __restrict__ hidden,
                            float* __restrict__ h0, float* __restrict__ h1,
                            unsigned long long* __restrict__ tokpk) {
    int idx = blockIdx.x * blockDim.x + threadIdx.x;
    if (idx < B_ * H_) {
        h0[idx] = hidden[idx];
        h1[idx] = hidden[B_ * H_ + idx];
    }
    if (idx < T_ * B_) tokpk[idx] = 0ull;
}

// GRU cell. Block owns 2 hidden columns; 256 thr = ks(16 K-splits) x
// [iloc(2) x bg(8, 4 batch each)]. Per thread: 4 batch x {sr,sz,an,hn}.
// mode==1: x rows gathered from embed via packed token; mode==0: x = xsrc.
template<int KX>
__global__ __launch_bounds__(256) void gru_kernel(
    const float* __restrict__ xsrc, const unsigned long long* __restrict__ tokprev,
    int t, int mode,
    const float* __restrict__ hprev,
    const float* __restrict__ Wih, const float* __restrict__ Whh,
    const float* __restrict__ bih, const float* __restrict__ bhh,
    float* __restrict__ hnew)
{
    const int tid  = threadIdx.x;
    const int ks   = tid >> 4;        // 0..15
    const int slot = tid & 15;        // 0..15
    const int iloc = slot >> 3;       // 0..1
    const int bg   = slot & 7;        // 0..7
    const int b0   = bg * 4;
    const int i    = blockIdx.x * 2 + iloc;

    const float* xb[4];
    #pragma unroll
    for (int j = 0; j < 4; j++) {
        if (mode) {
            int tok = 0;
            if (t > 0) {
                unsigned long long p = tokprev[b0 + j];
                tok = (int)(0xFFFFFFFFu - (unsigned int)(p & 0xFFFFFFFFull));
            }
            xb[j] = xsrc + (size_t)tok * KX;
        } else {
            xb[j] = xsrc + (size_t)(b0 + j) * KX;
        }
    }

    float sr[4] = {0,0,0,0}, sz[4] = {0,0,0,0}, an[4] = {0,0,0,0}, hn[4] = {0,0,0,0};

    // ---- x (input) part: K = KX ----
    {
        const float* wr = Wih + (size_t)(i) * KX;
        const float* wz = Wih + (size_t)(H_ + i) * KX;
        const float* wn = Wih + (size_t)(2 * H_ + i) * KX;
        const int kc = KX / 16;
        const int kend = (ks + 1) * kc;
        #pragma unroll 4
        for (int k = ks * kc; k < kend; k += 4) {
            f32x4 w_r = *(const f32x4*)(wr + k);
            f32x4 w_z = *(const f32x4*)(wz + k);
            f32x4 w_n = *(const f32x4*)(wn + k);
            #pragma unroll
            for (int j = 0; j < 4; j++) {
                f32x4 a = *(const f32x4*)(xb[j] + k);
                sr[j] += w_r.x*a.x + w_r.y*a.y + w_r.z*a.z + w_r.w*a.w;
                sz[j] += w_z.x*a.x + w_z.y*a.y + w_z.z*a.z + w_z.w*a.w;
                an[j] += w_n.x*a.x + w_n.y*a.y + w_n.z*a.z + w_n.w*a.w;
            }
        }
    }
    // ---- h (recurrent) part: K = H ----
    {
        const float* wr = Whh + (size_t)(i) * H_;
        const float* wz = Whh + (size_t)(H_ + i) * H_;
        const float* wn = Whh + (size_t)(2 * H_ + i) * H_;
        const int kc = H_ / 16;  // 64
        const int kend = (ks + 1) * kc;
        #pragma unroll 4
        for (int k = ks * kc; k < kend; k += 4) {
            f32x4 w_r = *(const f32x4*)(wr + k);
            f32x4 w_z = *(const f32x4*)(wz + k);
            f32x4 w_n = *(const f32x4*)(wn + k);
            #pragma unroll
            for (int j = 0; j < 4; j++) {
                const float* hb = hprev + (size_t)(b0 + j) * H_;
                f32x4 a = *(const f32x4*)(hb + k);
                sr[j] += w_r.x*a.x + w_r.y*a.y + w_r.z*a.z + w_r.w*a.w;
                sz[j] += w_z.x*a.x + w_z.y*a.y + w_z.z*a.z + w_z.w*a.w;
                hn[j] += w_n.x*a.x + w_n.y*a.y + w_n.z*a.z + w_n.w*a.w;
            }
        }
    }

    __shared__ float red[16][16][17];
    __shared__ float tot[16][17];
    {
        float* dst = &red[ks][slot][0];
        #pragma unroll
        for (int j = 0; j < 4; j++) {
            dst[j]      = sr[j];
            dst[4 + j]  = sz[j];
            dst[8 + j]  = an[j];
            dst[12 + j] = hn[j];
        }
    }
    __syncthreads();
    // stage 1: 256 threads, each sums one (slot, c) across 16 K-splits
    {
        const int s = tid >> 4, c = tid & 15;
        float ssum = 0.f;
        #pragma unroll
        for (int kk = 0; kk < 16; kk++) ssum += red[kk][s][c];
        tot[s][c] = ssum;
    }
    __syncthreads();
    // stage 2: 64 threads finalize (2 cols x 32 batch)
    if (tid < 64) {
        const int il = tid >> 5;
        const int b  = tid & 31;
        const int j  = b & 3;
        const int s  = il * 8 + (b >> 2);
        const int ii = blockIdx.x * 2 + il;
        float Sr = tot[s][j]      + bih[ii] + bhh[ii];
        float Sz = tot[s][4 + j]  + bih[H_ + ii] + bhh[H_ + ii];
        float An = tot[s][8 + j]  + bih[2 * H_ + ii];
        float Hn = tot[s][12 + j] + bhh[2 * H_ + ii];
        float r = 1.f / (1.f + expf(-Sr));
        float z = 1.f / (1.f + expf(-Sz));
        float n = tanhf(An + r * Hn);
        float hp = hprev[(size_t)b * H_ + ii];
        hnew[(size_t)b * H_ + ii] = (1.f - z) * n + z * hp;
    }
}

// Logits + fused argmax. Block tile: 16 vocab x 32 batch. 256 thr =
// ks(8 K-splits of 128) x [vloc(4, 4 vocab each) x bg(8, 4 batch each)].
__global__ __launch_bounds__(256) void logits_kernel(
    const float* __restrict__ h1, const float* __restrict__ Wout,
    const float* __restrict__ bout, float* __restrict__ out_t,
    unsigned long long* __restrict__ tokpk_t)
{
    const int tid  = threadIdx.x;
    const int ks   = tid >> 5;        // 0..7
    const int slot = tid & 31;        // 0..31
    const int vloc = slot >> 3;       // 0..3
    const int bg   = slot & 7;        // 0..7
    const int b0   = bg * 4;
    const int v    = blockIdx.x * 16 + vloc * 4;

    float acc[4][4];
    #pragma unroll
    for (int vi = 0; vi < 4; vi++)
        #pragma unroll
        for (int j = 0; j < 4; j++) acc[vi][j] = 0.f;

    const float* wp[4];
    const float* ap[4];
    #pragma unroll
    for (int vi = 0; vi < 4; vi++) wp[vi] = Wout + (size_t)(v + vi) * H_;
    #pragma unroll
    for (int j = 0; j < 4; j++) ap[j] = h1 + (size_t)(b0 + j) * H_;

    const int k0 = ks * 128, k1 = k0 + 128;
    #pragma unroll 4
    for (int k = k0; k < k1; k += 4) {
        f32x4 aa[4], ww[4];
        #pragma unroll
        for (int j = 0; j < 4; j++) aa[j] = *(const f32x4*)(ap[j] + k);
        #pragma unroll
        for (int vi = 0; vi < 4; vi++) ww[vi] = *(const f32x4*)(wp[vi] + k);
        #pragma unroll
        for (int vi = 0; vi < 4; vi++)
            #pragma unroll
            for (int j = 0; j < 4; j++)
                acc[vi][j] += ww[vi].x*aa[j].x + ww[vi].y*aa[j].y
                            + ww[vi].z*aa[j].z + ww[vi].w*aa[j].w;
    }

    __shared__ float red[8][32][17];
    __shared__ unsigned long long am[32][4];
    {
        float* dst = &red[ks][slot][0];
        #pragma unroll
        for (int vi = 0; vi < 4; vi++)
            #pragma unroll
            for (int j = 0; j < 4; j++) dst[vi * 4 + j] = acc[vi][j];
    }
    __syncthreads();
    if (tid < 32) {
        // thread == slot: sum 8 K-split slices for its 4 vocab x 4 batch
        float tot[4][4];
        #pragma unroll
        for (int vi = 0; vi < 4; vi++)
            #pragma unroll
            for (int j = 0; j < 4; j++) {
                float s = 0.f;
                #pragma unroll
                for (int kk = 0; kk < 8; kk++) s += red[kk][tid][vi * 4 + j];
                tot[vi][j] = s;
            }
        const int vv = blockIdx.x * 16 + (tid >> 3) * 4;
        const int bb0 = (tid & 7) * 4;
        float bo[4];
        #pragma unroll
        for (int vi = 0; vi < 4; vi++) bo[vi] = bout[vv + vi];
        #pragma unroll
        for (int vi = 0; vi < 4; vi++)
            #pragma unroll
            for (int j = 0; j < 4; j++) tot[vi][j] += bo[vi];

        // streaming (non-temporal) store of logits: don't pollute L3
        #pragma unroll
        for (int j = 0; j < 4; j++) {
            f32x4 o;
            o.x = tot[0][j]; o.y = tot[1][j]; o.z = tot[2][j]; o.w = tot[3][j];
            __builtin_nontemporal_store(o, (f32x4*)(out_t + (size_t)(bb0 + j) * V_ + vv));
        }
        // per-batch local argmax over this thread's 4 vocab cols
        #pragma unroll
        for (int j = 0; j < 4; j++) {
            unsigned long long best = 0ull;
            #pragma unroll
            for (int vi = 0; vi < 4; vi++) {
                unsigned long long p =
                    ((unsigned long long)fkey(tot[vi][j]) << 32)
                    | (unsigned long long)(0xFFFFFFFFu - (unsigned int)(vv + vi));
                best = (p > best) ? p : best;
            }
            am[bb0 + j][tid >> 3] = best;
        }
    }
    __syncthreads();
    if (tid < 32) {
        unsigned long long best = 0ull;
        #pragma unroll
        for (int q = 0; q < 4; q++) {
            unsigned long long p = am[tid][q];
            best = (p > best) ? p : best;
        }
        atomicMax(&tokpk_t[tid], best);
    }
}

extern "C" void kernel_launch(void* const* d_in, const int* in_sizes, int n_in,
                              void* d_out, int out_size, void* d_ws, size_t ws_size,
                              hipStream_t stream) {
    const float* hidden = (const float*)d_in[0];
    const float* embed  = (const float*)d_in[1];
    const float* Wih0   = (const float*)d_in[2];
    const float* Whh0   = (const float*)d_in[3];
    const float* bih0   = (const float*)d_in[4];
    const float* bhh0   = (const float*)d_in[5];
    const float* Wih1   = (const float*)d_in[6];
    const float* Whh1   = (const float*)d_in[7];
    const float* bih1   = (const float*)d_in[8];
    const float* bhh1   = (const float*)d_in[9];
    const float* Wout   = (const float*)d_in[10];
    const float* bout   = (const float*)d_in[11];
    float* out = (float*)d_out;

    float* ws = (float*)d_ws;
    float* h0buf = ws;                       // [2][B][H]
    float* h1buf = ws + 2 * B_ * H_;         // [2][B][H]
    unsigned long long* tokpk =
        (unsigned long long*)(ws + 4 * B_ * H_);  // [T][B]

    init_kernel<<<128, 256, 0, stream>>>(hidden, h0buf, h1buf, tokpk);

    for (int t = 0; t < T_; t++) {
        const int rp = t & 1, wpar = (t + 1) & 1;
        const unsigned long long* tokprev = tokpk + (size_t)(t > 0 ? t - 1 : 0) * B_;

        gru_kernel<E_><<<H_ / 2, 256, 0, stream>>>(
            embed, tokprev, t, /*mode=*/1,
            h0buf + (size_t)rp * B_ * H_,
            Wih0, Whh0, bih0, bhh0,
            h0buf + (size_t)wpar * B_ * H_);

        gru_kernel<H_><<<H_ / 2, 256, 0, stream>>>(
            h0buf + (size_t)wpar * B_ * H_, nullptr, 0, /*mode=*/0,
            h1buf + (size_t)rp * B_ * H_,
            Wih1, Whh1, bih1, bhh1,
            h1buf + (size_t)wpar * B_ * H_);

        logits_kernel<<<V_ / 16, 256, 0, stream>>>(
            h1buf + (size_t)wpar * B_ * H_, Wout, bout,
            out + (size_t)t * B_ * V_,
            tokpk + (size_t)t * B_);
    }
}

// Round 4
// 8964.035 us; speedup vs baseline: 1.0468x; 1.0179x over previous
//
#include <hip/hip_runtime.h>
#include <stdint.h>

#define V_ 16000
#define E_ 512
#define H_ 1024
#define B_ 32
#define T_ 64

typedef float f32x4 __attribute__((ext_vector_type(4)));

__device__ __forceinline__ unsigned int fkey(float f) {
    unsigned int u = __float_as_uint(f);
    return (u & 0x80000000u) ? ~u : (u | 0x80000000u);
}

__global__ void init_kernel(const float* __restrict__ hidden,
                            float* __restrict__ h0, float* __restrict__ h1,
                            unsigned long long* __restrict__ tokpk) {
    int idx = blockIdx.x * blockDim.x + threadIdx.x;
    if (idx < B_ * H_) {
        h0[idx] = hidden[idx];
        h1[idx] = hidden[B_ * H_ + idx];
    }
    if (idx < T_ * B_) tokpk[idx] = 0ull;
}

// GRU cell. Block owns 2 hidden cols. All 12 weight rows (6 Wih len KX,
// 6 Whh len H) are staged into LDS up front with coalesced 1KB wave loads
// (reg-staged async: global f32x4 -> ds_write). Compute: 16 ks K-splits with
// 16-bank-interleaved k so LDS reads are ~conflict-free; x/h read direct
// (L1/L2-hot). Reduce as in round 3.
template<int KX>
__global__ __launch_bounds__(256) void gru_kernel(
    const float* __restrict__ xsrc, const unsigned long long* __restrict__ tokprev,
    int t, int mode,
    const float* __restrict__ hprev,
    const float* __restrict__ Wih, const float* __restrict__ Whh,
    const float* __restrict__ bih, const float* __restrict__ bhh,
    float* __restrict__ hnew)
{
    constexpr int SWX  = KX + 8;          // padded LDS row stride (floats)
    constexpr int SWH  = H_ + 8;
    constexpr int CPRX = KX / 256;        // 1KB chunks per Wih row
    constexpr int CPRH = H_ / 256;        // = 4
    constexpr int NIX  = 6 * CPRX;        // Wih staging instrs
    constexpr int NTOT = NIX + 6 * CPRH;  // 36 (gru0) or 48 (gru1)
    constexpr int SPW  = NTOT / 4;        // instrs per wave: 9 or 12

    __shared__ float wlds[6 * SWX + 6 * SWH];
    __shared__ float red[16][16][17];
    __shared__ float tot[16][17];

    const int tid  = threadIdx.x;
    const int lane = tid & 63;
    const int wave = tid >> 6;
    const int c0   = blockIdx.x * 2;

    // ---- stage all weights: issue every load, then ds_write (async MLP) ----
    f32x4 tmp[SPW];
    int   dstw[SPW];
    #pragma unroll
    for (int s = 0; s < SPW; s++) {
        const int q = s * 4 + wave;
        const float* src;
        int dst;
        if (q < NIX) {
            const int rl = q / CPRX, ci = q % CPRX;   // rl = gate*2 + col
            const int g = rl >> 1, cl = rl & 1;
            src = Wih + (size_t)(g * H_ + c0 + cl) * KX + ci * 256 + lane * 4;
            dst = rl * SWX + ci * 256 + lane * 4;
        } else {
            const int q2 = q - NIX;
            const int rl = q2 >> 2, ci = q2 & 3;
            const int g = rl >> 1, cl = rl & 1;
            src = Whh + (size_t)(g * H_ + c0 + cl) * H_ + ci * 256 + lane * 4;
            dst = 6 * SWX + rl * SWH + ci * 256 + lane * 4;
        }
        tmp[s]  = *(const f32x4*)src;
        dstw[s] = dst;
    }
    #pragma unroll
    for (int s = 0; s < SPW; s++)
        *(f32x4*)&wlds[dstw[s]] = tmp[s];
    __syncthreads();

    // ---- compute ----
    const int ks   = tid >> 4;        // 0..15 K-split
    const int slot = tid & 15;        // iloc*8 + bg
    const int iloc = slot >> 3;       // 0..1
    const int bg   = slot & 7;        // 0..7
    const int b0   = bg * 4;

    const float* xb[4];
    #pragma unroll
    for (int j = 0; j < 4; j++) {
        if (mode) {
            int tok = 0;
            if (t > 0) {
                unsigned long long p = tokprev[b0 + j];
                tok = (int)(0xFFFFFFFFu - (unsigned int)(p & 0xFFFFFFFFull));
            }
            xb[j] = xsrc + (size_t)tok * KX;
        } else {
            xb[j] = xsrc + (size_t)(b0 + j) * KX;
        }
    }

    float sr[4] = {0,0,0,0}, sz[4] = {0,0,0,0}, an[4] = {0,0,0,0}, hn[4] = {0,0,0,0};

    // x (input) part: interleaved k = (i*16 + ks)*4
    {
        const float* wr = &wlds[(0 + iloc) * SWX];
        const float* wz = &wlds[(2 + iloc) * SWX];
        const float* wn = &wlds[(4 + iloc) * SWX];
        #pragma unroll 4
        for (int i = 0; i < KX / 64; i++) {
            const int kb = (i * 16 + ks) * 4;
            f32x4 w_r = *(const f32x4*)(wr + kb);
            f32x4 w_z = *(const f32x4*)(wz + kb);
            f32x4 w_n = *(const f32x4*)(wn + kb);
            #pragma unroll
            for (int j = 0; j < 4; j++) {
                f32x4 a = *(const f32x4*)(xb[j] + kb);
                sr[j] += w_r.x*a.x + w_r.y*a.y + w_r.z*a.z + w_r.w*a.w;
                sz[j] += w_z.x*a.x + w_z.y*a.y + w_z.z*a.z + w_z.w*a.w;
                an[j] += w_n.x*a.x + w_n.y*a.y + w_n.z*a.z + w_n.w*a.w;
            }
        }
    }
    // h (recurrent) part
    {
        const float* wr = &wlds[6 * SWX + (0 + iloc) * SWH];
        const float* wz = &wlds[6 * SWX + (2 + iloc) * SWH];
        const float* wn = &wlds[6 * SWX + (4 + iloc) * SWH];
        #pragma unroll 4
        for (int i = 0; i < H_ / 64; i++) {
            const int kb = (i * 16 + ks) * 4;
            f32x4 w_r = *(const f32x4*)(wr + kb);
            f32x4 w_z = *(const f32x4*)(wz + kb);
            f32x4 w_n = *(const f32x4*)(wn + kb);
            #pragma unroll
            for (int j = 0; j < 4; j++) {
                const float* hb = hprev + (size_t)(b0 + j) * H_;
                f32x4 a = *(const f32x4*)(hb + kb);
                sr[j] += w_r.x*a.x + w_r.y*a.y + w_r.z*a.z + w_r.w*a.w;
                sz[j] += w_z.x*a.x + w_z.y*a.y + w_z.z*a.z + w_z.w*a.w;
                hn[j] += w_n.x*a.x + w_n.y*a.y + w_n.z*a.z + w_n.w*a.w;
            }
        }
    }

    {
        float* dst = &red[ks][slot][0];
        #pragma unroll
        for (int j = 0; j < 4; j++) {
            dst[j]      = sr[j];
            dst[4 + j]  = sz[j];
            dst[8 + j]  = an[j];
            dst[12 + j] = hn[j];
        }
    }
    __syncthreads();
    {
        const int s = tid >> 4, c = tid & 15;
        float ssum = 0.f;
        #pragma unroll
        for (int kk = 0; kk < 16; kk++) ssum += red[kk][s][c];
        tot[s][c] = ssum;
    }
    __syncthreads();
    if (tid < 64) {
        const int il = tid >> 5;
        const int b  = tid & 31;
        const int j  = b & 3;
        const int s  = il * 8 + (b >> 2);
        const int ii = blockIdx.x * 2 + il;
        float Sr = tot[s][j]      + bih[ii] + bhh[ii];
        float Sz = tot[s][4 + j]  + bih[H_ + ii] + bhh[H_ + ii];
        float An = tot[s][8 + j]  + bih[2 * H_ + ii];
        float Hn = tot[s][12 + j] + bhh[2 * H_ + ii];
        float r = 1.f / (1.f + expf(-Sr));
        float z = 1.f / (1.f + expf(-Sz));
        float n = tanhf(An + r * Hn);
        float hp = hprev[(size_t)b * H_ + ii];
        hnew[(size_t)b * H_ + ii] = (1.f - z) * n + z * hp;
    }
}

// Logits + argmax. Block: 32 vocab rows x 32 batch, K=1024 in 4 chunks of 256.
// W chunks double-buffered in LDS (reg-staged coalesced 1KB wave loads, T14
// order: load next -> compute cur -> write next -> barrier). h1 read direct.
// Per-thread tile 4v x 4b with v-rows strided by 8 (conflict-free LDS reads
// at row stride 260).
__global__ __launch_bounds__(256) void logits_kernel(
    const float* __restrict__ h1, const float* __restrict__ Wout,
    const float* __restrict__ bout, float* __restrict__ out_t,
    unsigned long long* __restrict__ tokpk_t)
{
    constexpr int SWL = 260;                 // LDS row stride (floats)
    constexpr int KC  = 256;                 // chunk K
    constexpr int NC  = H_ / KC;             // 4
    __shared__ float lds_raw[2 * 32 * SWL];  // 66560 B, reduce overlays after

    const int tid  = threadIdx.x;
    const int lane = tid & 63;
    const int wave = tid >> 6;
    const int v0   = blockIdx.x * 32;

    const int ks = wave;              // k-quarter (64) within chunk
    const int vg = (tid & 63) >> 3;   // 0..7 ; thread v-rows = vg + 8*vi
    const int bg = tid & 7;
    const int b0 = bg * 4;

    float acc[4][4];
    #pragma unroll
    for (int vi = 0; vi < 4; vi++)
        #pragma unroll
        for (int j = 0; j < 4; j++) acc[vi][j] = 0.f;

    const float* ap[4];
    #pragma unroll
    for (int j = 0; j < 4; j++) ap[j] = h1 + (size_t)(b0 + j) * H_;

    f32x4 st[8];
    auto load_chunk = [&](int c) {
        #pragma unroll
        for (int s = 0; s < 8; s++) {
            const int r = wave * 8 + s;
            st[s] = *(const f32x4*)(Wout + (size_t)(v0 + r) * H_ + c * KC + lane * 4);
        }
    };
    auto write_chunk = [&](int buf) {
        float* dstb = &lds_raw[buf * 32 * SWL];
        #pragma unroll
        for (int s = 0; s < 8; s++) {
            const int r = wave * 8 + s;
            *(f32x4*)&dstb[r * SWL + lane * 4] = st[s];
        }
    };

    load_chunk(0);
    write_chunk(0);
    __syncthreads();

    int cur = 0;
    for (int c = 0; c < NC; c++) {
        if (c + 1 < NC) load_chunk(c + 1);
        const float* wb = &lds_raw[cur * 32 * SWL];
        const int kq = ks * 64;
        #pragma unroll 4
        for (int kk = 0; kk < 16; kk++) {
            const int kb = kq + kk * 4;
            const int kg = c * KC + kb;
            f32x4 ww[4];
            #pragma unroll
            for (int vi = 0; vi < 4; vi++)
                ww[vi] = *(const f32x4*)&wb[(vg + 8 * vi) * SWL + kb];
            #pragma unroll
            for (int j = 0; j < 4; j++) {
                f32x4 a = *(const f32x4*)(ap[j] + kg);
                #pragma unroll
                for (int vi = 0; vi < 4; vi++)
                    acc[vi][j] += ww[vi].x*a.x + ww[vi].y*a.y
                                + ww[vi].z*a.z + ww[vi].w*a.w;
            }
        }
        if (c + 1 < NC) write_chunk(cur ^ 1);
        __syncthreads();
        cur ^= 1;
    }

    // ---- reduce (overlay onto lds_raw; last barrier above protects it) ----
    float* red  = lds_raw;                        // [4][64][17]
    float* totl = lds_raw + 4 * 64 * 17;          // [32][33]
    unsigned long long* am =
        (unsigned long long*)(lds_raw + 4 * 64 * 17 + 32 * 33);  // [32][8]

    {
        float* dst = &red[(ks * 64 + vg * 8 + bg) * 17];
        #pragma unroll
        for (int vi = 0; vi < 4; vi++)
            #pragma unroll
            for (int j = 0; j < 4; j++) dst[vi * 4 + j] = acc[vi][j];
    }
    __syncthreads();
    if (tid < 64) {
        const int vgr = tid >> 3, bgr = tid & 7;
        float tv[16];
        #pragma unroll
        for (int c2 = 0; c2 < 16; c2++) {
            float s = 0.f;
            #pragma unroll
            for (int k2 = 0; k2 < 4; k2++) s += red[(k2 * 64 + tid) * 17 + c2];
            tv[c2] = s;
        }
        #pragma unroll
        for (int vi = 0; vi < 4; vi++) {
            float bo = bout[v0 + vgr + 8 * vi];
            #pragma unroll
            for (int j = 0; j < 4; j++) tv[vi * 4 + j] += bo;
        }
        #pragma unroll
        for (int vi = 0; vi < 4; vi++)
            #pragma unroll
            for (int j = 0; j < 4; j++)
                totl[(bgr * 4 + j) * 33 + (vgr + 8 * vi)] = tv[vi * 4 + j];
        #pragma unroll
        for (int j = 0; j < 4; j++) {
            unsigned long long best = 0ull;
            #pragma unroll
            for (int vi = 0; vi < 4; vi++) {
                const int v = v0 + vgr + 8 * vi;
                unsigned long long p =
                    ((unsigned long long)fkey(tv[vi * 4 + j]) << 32)
                    | (unsigned long long)(0xFFFFFFFFu - (unsigned int)v);
                best = (p > best) ? p : best;
            }
            am[(bgr * 4 + j) * 8 + vgr] = best;
        }
    }
    __syncthreads();
    if (tid < 64) {
        const int b = tid >> 1, half = tid & 1;
        #pragma unroll
        for (int q = 0; q < 4; q++) {
            f32x4 o;
            o.x = totl[b * 33 + half * 16 + q * 4 + 0];
            o.y = totl[b * 33 + half * 16 + q * 4 + 1];
            o.z = totl[b * 33 + half * 16 + q * 4 + 2];
            o.w = totl[b * 33 + half * 16 + q * 4 + 3];
            __builtin_nontemporal_store(
                o, (f32x4*)(out_t + (size_t)b * V_ + v0 + half * 16 + q * 4));
        }
    }
    if (tid < 32) {
        unsigned long long best = 0ull;
        #pragma unroll
        for (int q = 0; q < 8; q++) {
            unsigned long long p = am[tid * 8 + q];
            best = (p > best) ? p : best;
        }
        atomicMax(&tokpk_t[tid], best);
    }
}

extern "C" void kernel_launch(void* const* d_in, const int* in_sizes, int n_in,
                              void* d_out, int out_size, void* d_ws, size_t ws_size,
                              hipStream_t stream) {
    const float* hidden = (const float*)d_in[0];
    const float* embed  = (const float*)d_in[1];
    const float* Wih0   = (const float*)d_in[2];
    const float* Whh0   = (const float*)d_in[3];
    const float* bih0   = (const float*)d_in[4];
    const float* bhh0   = (const float*)d_in[5];
    const float* Wih1   = (const float*)d_in[6];
    const float* Whh1   = (const float*)d_in[7];
    const float* bih1   = (const float*)d_in[8];
    const float* bhh1   = (const float*)d_in[9];
    const float* Wout   = (const float*)d_in[10];
    const float* bout   = (const float*)d_in[11];
    float* out = (float*)d_out;

    float* ws = (float*)d_ws;
    float* h0buf = ws;                       // [2][B][H]
    float* h1buf = ws + 2 * B_ * H_;         // [2][B][H]
    unsigned long long* tokpk =
        (unsigned long long*)(ws + 4 * B_ * H_);  // [T][B]

    init_kernel<<<128, 256, 0, stream>>>(hidden, h0buf, h1buf, tokpk);

    for (int t = 0; t < T_; t++) {
        const int rp = t & 1, wpar = (t + 1) & 1;
        const unsigned long long* tokprev = tokpk + (size_t)(t > 0 ? t - 1 : 0) * B_;

        gru_kernel<E_><<<H_ / 2, 256, 0, stream>>>(
            embed, tokprev, t, /*mode=*/1,
            h0buf + (size_t)rp * B_ * H_,
            Wih0, Whh0, bih0, bhh0,
            h0buf + (size_t)wpar * B_ * H_);

        gru_kernel<H_><<<H_ / 2, 256, 0, stream>>>(
            h0buf + (size_t)wpar * B_ * H_, nullptr, 0, /*mode=*/0,
            h1buf + (size_t)rp * B_ * H_,
            Wih1, Whh1, bih1, bhh1,
            h1buf + (size_t)wpar * B_ * H_);

        logits_kernel<<<V_ / 32, 256, 0, stream>>>(
            h1buf + (size_t)wpar * B_ * H_, Wout, bout,
            out + (size_t)t * B_ * V_,
            tokpk + (size_t)t * B_);
    }
}

// Round 5
// 4373.811 us; speedup vs baseline: 2.1454x; 2.0495x over previous
//
#include <hip/hip_runtime.h>
#include <stdint.h>

#define V_ 16000
#define E_ 512
#define H_ 1024
#define B_ 32
#define T_ 64
#define NG_ 3072        // 3*H rows per weight matrix
#define NR_ 6144        // virtual rows in gru gemm (ih + hh)
#define IHB_ 96         // ih blocks (3072/32)

typedef float f32x4 __attribute__((ext_vector_type(4)));
typedef unsigned long long u64;

__device__ __forceinline__ unsigned int fkey(float f) {
    unsigned int u = __float_as_uint(f);
    return (u & 0x80000000u) ? ~u : (u | 0x80000000u);
}

__global__ void init_kernel(const float* __restrict__ hidden,
                            float* __restrict__ h0, float* __restrict__ h1,
                            u64* __restrict__ tokpk) {
    int idx = blockIdx.x * blockDim.x + threadIdx.x;
    if (idx < B_ * H_) {
        h0[idx] = hidden[idx];
        h1[idx] = hidden[B_ * H_ + idx];
    }
    if (idx < T_ * B_) tokpk[idx] = 0ull;
}

// ---------------------------------------------------------------------------
// Streamed [32 rows x 32 batch x K] GEMM core. 256 threads.
//   ks = tid>>6 (4-way k-split by wave); lane: vg = (tid&63)>>3, bg = tid&7.
//   acc[vi][j] covers W-row (vg+8vi), batch (bg+8j) -- partial over ks slice.
// LDS: 8192 floats (32KB): buf b at b*4096 = [W 32x64 | A 32x64], f32x4 slots
// XOR-swizzled by (row&7) so compute reads are bank-conflict-free.
// Per chunk (64 k): each thread stages 2 W + 2 A f32x4 (coalesced 1KB/wave
// per operand-half); loads for chunk c+1 issued BEFORE compute of chunk c
// (continuous deep MLP), ds_write after, single barrier per chunk.
// ---------------------------------------------------------------------------
__device__ __forceinline__ void gemm_core(
    const float* wp0, const float* wp1,   // W row ptrs (rows tid>>4, tid>>4+16)
    const float* ap0, const float* ap1,   // A row ptrs (rows tid>>4, tid>>4+16)
    int nch, float* lds, int tid, float acc[4][4])
{
    const int k4s = tid & 15;
    const int r   = tid >> 4;
    const int dW0 = (r << 6) + ((k4s ^ (r & 7)) << 2);
    const int dW1 = dW0 + (16 << 6);          // (r+16)&7 == r&7
    const int ks   = tid >> 6;
    const int lane = tid & 63;
    const int vg = lane >> 3, bg = lane & 7;

    f32x4 tW0, tW1, tA0, tA1;
    tW0 = *(const f32x4*)(wp0 + (k4s << 2));
    tW1 = *(const f32x4*)(wp1 + (k4s << 2));
    tA0 = *(const f32x4*)(ap0 + (k4s << 2));
    tA1 = *(const f32x4*)(ap1 + (k4s << 2));
    *(f32x4*)&lds[dW0] = tW0;        *(f32x4*)&lds[dW1] = tW1;
    *(f32x4*)&lds[2048 + dW0] = tA0; *(f32x4*)&lds[2048 + dW1] = tA1;
    __syncthreads();

    int cur = 0;
    for (int c = 0; c < nch; c++) {
        if (c + 1 < nch) {
            const int nko = (c + 1) << 6;
            tW0 = *(const f32x4*)(wp0 + nko + (k4s << 2));
            tW1 = *(const f32x4*)(wp1 + nko + (k4s << 2));
            tA0 = *(const f32x4*)(ap0 + nko + (k4s << 2));
            tA1 = *(const f32x4*)(ap1 + nko + (k4s << 2));
        }
        const float* Wb = &lds[cur * 4096];
        const float* Ab = &lds[cur * 4096 + 2048];
        #pragma unroll
        for (int kk = 0; kk < 4; kk++) {
            const int k4 = ks * 4 + kk;
            f32x4 ww[4], ha[4];
            #pragma unroll
            for (int vi = 0; vi < 4; vi++)
                ww[vi] = *(const f32x4*)&Wb[((vg + 8*vi) << 6) + ((k4 ^ vg) << 2)];
            #pragma unroll
            for (int j = 0; j < 4; j++)
                ha[j] = *(const f32x4*)&Ab[((bg + 8*j) << 6) + ((k4 ^ bg) << 2)];
            #pragma unroll
            for (int vi = 0; vi < 4; vi++)
                #pragma unroll
                for (int j = 0; j < 4; j++)
                    acc[vi][j] += ww[vi].x*ha[j].x + ww[vi].y*ha[j].y
                                + ww[vi].z*ha[j].z + ww[vi].w*ha[j].w;
        }
        if (c + 1 < nch) {
            float* Wo = &lds[(cur ^ 1) * 4096];
            *(f32x4*)&Wo[dW0] = tW0;        *(f32x4*)&Wo[dW1] = tW1;
            *(f32x4*)&Wo[2048 + dW0] = tA0; *(f32x4*)&Wo[2048 + dW1] = tA1;
        }
        __syncthreads();
        cur ^= 1;
    }
}

// Sum the 4 ks partials via LDS overlay (lds free after gemm_core's last
// barrier). On exit threads tid<64 hold tv[16] = full sums for
// (row vgr+8vi, batch bgr+8j), vgr=tid>>3, bgr=tid&7.
__device__ __forceinline__ void ks_reduce(float* lds, int tid,
                                          float acc[4][4], float tv[16])
{
    const int ks = tid >> 6, lane = tid & 63;
    float* red = lds;                          // [4][64][17]
    float* dst = &red[(ks * 64 + lane) * 17];
    #pragma unroll
    for (int vi = 0; vi < 4; vi++)
        #pragma unroll
        for (int j = 0; j < 4; j++) dst[vi*4 + j] = acc[vi][j];
    __syncthreads();
    if (tid < 64) {
        #pragma unroll
        for (int c = 0; c < 16; c++) {
            float s = 0.f;
            #pragma unroll
            for (int k = 0; k < 4; k++) s += red[(k*64 + tid)*17 + c];
            tv[c] = s;
        }
    }
}

// GRU GEMM: virtual N = 6144 rows. Blocks [0,96): gi = x @ Wih^T rows;
// blocks [96,192): gh = h_prev @ Whh^T rows. Writes gbuf[b][n] (no bias).
__global__ __launch_bounds__(256) void gemm_gru(
    const float* __restrict__ Wih, const float* __restrict__ Whh, int Kih,
    const float* __restrict__ xbase, int xld,
    const float* __restrict__ embed, const u64* __restrict__ tokprev,
    int t, int tmode,
    const float* __restrict__ hprev,
    float* __restrict__ gbuf)
{
    __shared__ float lds[8192];
    const int tid = threadIdx.x;
    const int blk = blockIdx.x;
    const int r = tid >> 4;

    const float *wp0, *wp1, *ap0, *ap1;
    int nch;
    if (blk < IHB_) {
        const int n0 = blk * 32;
        wp0 = Wih + (size_t)(n0 + r) * Kih;
        wp1 = Wih + (size_t)(n0 + r + 16) * Kih;
        if (tmode) {
            int tok0 = 0, tok1 = 0;
            if (t > 0) {
                tok0 = (int)(0xFFFFFFFFu - (unsigned)(tokprev[r] & 0xFFFFFFFFull));
                tok1 = (int)(0xFFFFFFFFu - (unsigned)(tokprev[r + 16] & 0xFFFFFFFFull));
            }
            ap0 = embed + (size_t)tok0 * Kih;   // Kih == E_ for layer 0
            ap1 = embed + (size_t)tok1 * Kih;
        } else {
            ap0 = xbase + (size_t)r * xld;
            ap1 = xbase + (size_t)(r + 16) * xld;
        }
        nch = Kih >> 6;
    } else {
        const int n0 = (blk - IHB_) * 32;
        wp0 = Whh + (size_t)(n0 + r) * H_;
        wp1 = Whh + (size_t)(n0 + r + 16) * H_;
        ap0 = hprev + (size_t)r * H_;
        ap1 = hprev + (size_t)(r + 16) * H_;
        nch = H_ >> 6;
    }

    float acc[4][4] = {};
    gemm_core(wp0, wp1, ap0, ap1, nch, lds, tid, acc);
    float tv[16];
    ks_reduce(lds, tid, acc, tv);
    if (tid < 64) {
        const int vgr = tid >> 3, bgr = tid & 7;
        const int nout0 = blk * 32;
        #pragma unroll
        for (int vi = 0; vi < 4; vi++)
            #pragma unroll
            for (int j = 0; j < 4; j++)
                gbuf[(size_t)(bgr + 8*j) * NR_ + nout0 + vgr + 8*vi] = tv[vi*4+j];
    }
}

// GRU elementwise combine: h' = (1-z)*n + z*h. One (b,i) per thread.
__global__ __launch_bounds__(256) void combine_kernel(
    const float* __restrict__ gbuf,
    const float* __restrict__ bih, const float* __restrict__ bhh,
    const float* __restrict__ hprev, float* __restrict__ hnew)
{
    const int idx = blockIdx.x * 256 + threadIdx.x;   // 0..32767
    const int b = idx >> 10, i = idx & 1023;
    const float* gb = gbuf + (size_t)b * NR_;
    const float gir = gb[i],        giz = gb[H_ + i],        gin = gb[2*H_ + i];
    const float ghr = gb[NG_ + i],  ghz = gb[NG_ + H_ + i],  ghn = gb[NG_ + 2*H_ + i];
    const float Sr = gir + ghr + bih[i] + bhh[i];
    const float Sz = giz + ghz + bih[H_ + i] + bhh[H_ + i];
    const float rr = 1.f / (1.f + expf(-Sr));
    const float zz = 1.f / (1.f + expf(-Sz));
    const float nn = tanhf(gin + bih[2*H_ + i] + rr * (ghn + bhh[2*H_ + i]));
    const float hp = hprev[(size_t)b * H_ + i];
    hnew[(size_t)b * H_ + i] = (1.f - zz) * nn + zz * hp;
}

// Logits (32 vocab rows / block) + bias + nt-store + fused argmax.
__global__ __launch_bounds__(256) void logits_kernel(
    const float* __restrict__ h1, const float* __restrict__ Wout,
    const float* __restrict__ bout, float* __restrict__ out_t,
    u64* __restrict__ tokpk_t)
{
    __shared__ float lds[8192];
    const int tid = threadIdx.x;
    const int r = tid >> 4;
    const int v0 = blockIdx.x * 32;
    const float* wp0 = Wout + (size_t)(v0 + r) * H_;
    const float* wp1 = Wout + (size_t)(v0 + r + 16) * H_;
    const float* ap0 = h1 + (size_t)r * H_;
    const float* ap1 = h1 + (size_t)(r + 16) * H_;

    float acc[4][4] = {};
    gemm_core(wp0, wp1, ap0, ap1, H_ >> 6, lds, tid, acc);
    float tv[16];
    ks_reduce(lds, tid, acc, tv);

    float* totl = lds + 4*64*17;                        // [32][33]
    u64*   am   = (u64*)(lds + 4*64*17 + 32*33);        // [32][8]
    if (tid < 64) {
        const int vgr = tid >> 3, bgr = tid & 7;
        #pragma unroll
        for (int vi = 0; vi < 4; vi++) {
            const float bo = bout[v0 + vgr + 8*vi];
            #pragma unroll
            for (int j = 0; j < 4; j++) tv[vi*4+j] += bo;
        }
        #pragma unroll
        for (int vi = 0; vi < 4; vi++)
            #pragma unroll
            for (int j = 0; j < 4; j++)
                totl[(bgr + 8*j) * 33 + vgr + 8*vi] = tv[vi*4+j];
        #pragma unroll
        for (int j = 0; j < 4; j++) {
            u64 best = 0ull;
            #pragma unroll
            for (int vi = 0; vi < 4; vi++) {
                const int v = v0 + vgr + 8*vi;
                u64 p = ((u64)fkey(tv[vi*4+j]) << 32)
                      | (u64)(0xFFFFFFFFu - (unsigned)v);
                best = p > best ? p : best;
            }
            am[(bgr + 8*j) * 8 + vgr] = best;
        }
    }
    __syncthreads();
    if (tid < 64) {
        const int b = tid >> 1, half = tid & 1;
        #pragma unroll
        for (int q = 0; q < 4; q++) {
            f32x4 o;
            o.x = totl[b*33 + half*16 + q*4 + 0];
            o.y = totl[b*33 + half*16 + q*4 + 1];
            o.z = totl[b*33 + half*16 + q*4 + 2];
            o.w = totl[b*33 + half*16 + q*4 + 3];
            __builtin_nontemporal_store(
                o, (f32x4*)(out_t + (size_t)b * V_ + v0 + half*16 + q*4));
        }
    }
    if (tid < 32) {
        u64 best = 0ull;
        #pragma unroll
        for (int q = 0; q < 8; q++) {
            u64 p = am[tid*8 + q];
            best = p > best ? p : best;
        }
        atomicMax(&tokpk_t[tid], best);
    }
}

extern "C" void kernel_launch(void* const* d_in, const int* in_sizes, int n_in,
                              void* d_out, int out_size, void* d_ws, size_t ws_size,
                              hipStream_t stream) {
    const float* hidden = (const float*)d_in[0];
    const float* embed  = (const float*)d_in[1];
    const float* Wih0   = (const float*)d_in[2];
    const float* Whh0   = (const float*)d_in[3];
    const float* bih0   = (const float*)d_in[4];
    const float* bhh0   = (const float*)d_in[5];
    const float* Wih1   = (const float*)d_in[6];
    const float* Whh1   = (const float*)d_in[7];
    const float* bih1   = (const float*)d_in[8];
    const float* bhh1   = (const float*)d_in[9];
    const float* Wout   = (const float*)d_in[10];
    const float* bout   = (const float*)d_in[11];
    float* out = (float*)d_out;

    const int BH = B_ * H_;
    float* ws = (float*)d_ws;
    float* h0buf = ws;                        // [2][B][H]
    float* h1buf = ws + 2 * BH;               // [2][B][H]
    float* gbuf  = ws + 4 * BH;               // [B][NR_]
    u64* tokpk = (u64*)(ws + 4 * BH + B_ * NR_);  // [T][B]

    init_kernel<<<128, 256, 0, stream>>>(hidden, h0buf, h1buf, tokpk);

    for (int t = 0; t < T_; t++) {
        const int rp = t & 1, wpar = (t + 1) & 1;
        const u64* tokprev = tokpk + (size_t)(t > 0 ? t - 1 : 0) * B_;

        // layer 0: x = embed[tok]
        gemm_gru<<<NR_ / 32, 256, 0, stream>>>(
            Wih0, Whh0, E_, nullptr, 0, embed, tokprev, t, /*tmode=*/1,
            h0buf + (size_t)rp * BH, gbuf);
        combine_kernel<<<128, 256, 0, stream>>>(
            gbuf, bih0, bhh0, h0buf + (size_t)rp * BH, h0buf + (size_t)wpar * BH);

        // layer 1: x = h0'
        gemm_gru<<<NR_ / 32, 256, 0, stream>>>(
            Wih1, Whh1, H_, h0buf + (size_t)wpar * BH, H_, embed, tokprev, 0,
            /*tmode=*/0, h1buf + (size_t)rp * BH, gbuf);
        combine_kernel<<<128, 256, 0, stream>>>(
            gbuf, bih1, bhh1, h1buf + (size_t)rp * BH, h1buf + (size_t)wpar * BH);

        logits_kernel<<<V_ / 32, 256, 0, stream>>>(
            h1buf + (size_t)wpar * BH, Wout, bout,
            out + (size_t)t * B_ * V_, tokpk + (size_t)t * B_);
    }
}